// Round 1
// 316.017 us; speedup vs baseline: 1.0121x; 1.0121x over previous
//
#include <hip/hip_runtime.h>

#define BB 8
#define CC 64
#define HH 128
#define WW 128
#define TT 3
#define LL 4
#define MM 3

#define PW 130                    // padded spatial dim
#define IMGH ((size_t)PW * PW * CC)   // halves per padded image

typedef _Float16 half8 __attribute__((ext_vector_type(8)));
typedef _Float16 half4 __attribute__((ext_vector_type(4)));
typedef float floatx16 __attribute__((ext_vector_type(16)));

__device__ __forceinline__ void async_ld16(const _Float16* g, _Float16* l) {
    __builtin_amdgcn_global_load_lds(
        (const __attribute__((address_space(1))) void*)g,
        (__attribute__((address_space(3))) void*)l, 16, 0, 0);
}

// ---------------------------------------------------------------------------
// Routing: argmax over (a + g), chained on previous index.
// ---------------------------------------------------------------------------
__global__ void routing_kernel(const float* __restrict__ alpha0,
                               const float* __restrict__ alphas,
                               const float* __restrict__ g0,
                               const float* __restrict__ gs,
                               int* __restrict__ sel) // [T][L]
{
    if (blockIdx.x != 0 || threadIdx.x != 0) return;
    for (int t = 0; t < TT; ++t) {
        int idx = 0;
        for (int layer = 0; layer < LL; ++layer) {
            const float *a, *g;
            if (layer == 0) { a = alpha0 + t * MM; g = g0 + t * MM; }
            else {
                int off = (((layer - 1) * TT + t) * MM + idx) * MM;
                a = alphas + off; g = gs + off;
            }
            float best = a[0] + g[0];
            int bi = 0;
            for (int j = 1; j < MM; ++j) {
                float v = a[j] + g[j];
                if (v > best) { best = v; bi = j; }
            }
            sel[t * LL + layer] = bi;
            idx = bi;
        }
    }
}

// ---------------------------------------------------------------------------
// Weight prep: gather selected modules, fp32 -> fp16, rearrange to A-frag
// order: W3[tl][tap][c(2)][il(2)][o(2)][lane(64)*8] -- one a-frag = one
// contiguous 1 KB wave-load.  i = tap*4096 + c*2048 + il*1024 + o*512 + l*8 + j
// ---------------------------------------------------------------------------
__global__ __launch_bounds__(256) void prep_weights(
    const float* __restrict__ enc_w, // [L][M][64][64][3][3]
    const int* __restrict__ sel,
    _Float16* __restrict__ W3)       // [12][36864]
{
    int tl = blockIdx.y;
    int t = tl >> 2, layer = tl & 3;
    int m = sel[t * LL + layer];
    const float* src = enc_w + ((size_t)layer * MM + m) * (CC * CC * 9);
    _Float16* dst = W3 + (size_t)tl * 36864;
    for (int i = blockIdx.x * 256 + threadIdx.x; i < 36864; i += gridDim.x * 256) {
        int j   = i & 7;
        int l   = (i >> 3) & 63;
        int o   = (i >> 9) & 1;
        int il  = (i >> 10) & 1;
        int c   = (i >> 11) & 1;
        int tap = i >> 12;                      // 0..8
        int oc  = o * 32 + (l & 31);
        int kch = c * 32 + il * 16 + (l >> 5) * 8 + j;
        dst[i] = (_Float16)src[(oc * CC + kch) * 9 + tap];
    }
}

// ---------------------------------------------------------------------------
// Zero the 1-px borders of nimg padded NHWC images (contiguous buffers).
// Interior is (over)written by producers; borders must be 0 for SAME conv.
// ---------------------------------------------------------------------------
__global__ __launch_bounds__(256) void zero_borders(_Float16* __restrict__ base0)
{
    _Float16* base = base0 + (size_t)blockIdx.x * IMGH;
    const int i0 = blockIdx.y * 1032;
    for (int i = i0 + threadIdx.x; i < i0 + 1032; i += 256) {
        int px_idx = i >> 3, q = i & 7;   // 516 border px * 8 half8-chunks
        int row, col;
        if (px_idx < 130)      { row = 0;            col = px_idx; }
        else if (px_idx < 260) { row = 129;          col = px_idx - 130; }
        else if (px_idx < 388) { row = px_idx - 259; col = 0; }
        else                   { row = px_idx - 387; col = 129; }
        half8 z = {};
        *(half8*)(base + ((size_t)row * PW + col) * CC + q * 8) = z;
    }
}

// ---------------------------------------------------------------------------
// x: NCHW fp32 -> padded NHWC f16 (interior). Lane = px, LDS transpose.
// ---------------------------------------------------------------------------
__global__ __launch_bounds__(256) void to_nhwc(
    const float* __restrict__ x,    // [B][64][128][128]
    _Float16* __restrict__ act0)    // [B][130][130][64] padded
{
    const int xs = blockIdx.x;  // 0..1
    const int y  = blockIdx.y;  // 0..127
    const int b  = blockIdx.z;  // 0..7

    __shared__ _Float16 lds[64 * 72];  // [px][ch], pad 72

    const int wv = threadIdx.x >> 6;
    const int l  = threadIdx.x & 63;
    const float* src = x + ((size_t)b * CC * HH + y) * WW + xs * 64 + l;
#pragma unroll
    for (int k = 0; k < 16; ++k) {
        int ch = wv * 16 + k;
        lds[l * 72 + ch] = (_Float16)src[(size_t)ch * HH * WW];
    }
    __syncthreads();
    int px = threadIdx.x >> 2;
    int q  = threadIdx.x & 3;
    _Float16* dst = act0 + (size_t)b * IMGH
                  + ((size_t)(y + 1) * PW + xs * 64 + px + 1) * CC + q * 16;
    *(half8*)dst       = *(const half8*)&lds[px * 72 + q * 16];
    *(half8*)(dst + 8) = *(const half8*)&lds[px * 72 + q * 16 + 8];
}

// ---------------------------------------------------------------------------
// 3x3 SAME conv + bias + ReLU on padded NHWC f16 buffers, MFMA 32x32x16.
// Block 256 thr / 4 waves: 4 output rows x 64 px x 64 oc (wave = one row).
// NEW STRUCTURE: both 32-ch input chunks DMA-staged up-front via
// global_load_lds into a 2x25.6KB LDS buffer (linear dest, XOR-swizzled
// 16B channel slots so the b128 reads are bank-conflict-free), then ONE
// __syncthreads and 18 back-to-back tap phases (144 MFMA/wave), no mid
// barriers.  Weight a-frags prefetched 1 phase ahead from W3 (L2-hot).
// ---------------------------------------------------------------------------
__global__ __launch_bounds__(256, 3) void conv3x3_mfma(
    const _Float16* __restrict__ in,   // padded NHWC per task (stride tsi halves)
    _Float16* __restrict__ out,        // padded NHWC per task (stride tso halves)
    const _Float16* __restrict__ W3,   // [12][36864]
    const float* __restrict__ enc_b,   // [L][M][64]
    const int* __restrict__ sel,
    int layer, int task0, size_t tsi, size_t tso)
{
    const int y0  = (blockIdx.x >> 1) * 4;   // padded row of halo top (=orig y0-1+1)
    const int px0 = (blockIdx.x & 1) * 64;   // padded col of halo left
    const int b   = blockIdx.y;
    const int tz  = blockIdx.z;
    const int t   = task0 + tz;

    const _Float16* inp = in + (size_t)tz * tsi + (size_t)b * IMGH;
    _Float16* outp      = out + (size_t)tz * tso + (size_t)b * IMGH;
    const int tl = t * LL + layer;
    const _Float16* Wt = W3 + (size_t)tl * 36864;

    const int tid  = threadIdx.x;
    const int lane = tid & 63;
    const int w    = tid >> 6;        // wave = output row within block
    const int n    = lane & 31;
    const int ksub = lane >> 5;

    // chunk buffer: [6 rows][66 px][4 slots][16B], slot s holds c8 = s ^ swz(px)
    // 1584 slots data + 16 pad slots = 25600 B per chunk; two chunks.
    __shared__ __align__(16) _Float16 lds[2 * 12800];

    floatx16 acc[2][2];
#pragma unroll
    for (int o = 0; o < 2; ++o)
#pragma unroll
        for (int j = 0; j < 2; ++j)
#pragma unroll
            for (int i = 0; i < 16; ++i) acc[o][j][i] = 0.f;

    half8 a_cur[4], a_nxt[4];   // [o*2+il]

#define WFRAG(c, tap, o, il) \
    (*(const half8*)(Wt + ((((size_t)(tap) * 2 + (c)) * 2 + (il)) * 2 + (o)) * 512 + lane * 8))

    // issue first-phase weight loads before staging so they drain with it
#pragma unroll
    for (int o = 0; o < 2; ++o)
#pragma unroll
        for (int il = 0; il < 2; ++il) a_cur[o * 2 + il] = WFRAG(0, 0, o, il);

    // ---- DMA-stage BOTH chunks: 2 x 25 wave-ops of 1KB each ----
#pragma unroll
    for (int c = 0; c < 2; ++c) {
        for (int j = w; j < 25; j += 4) {
            int idx = j * 64 + lane;          // slot index 0..1599
            int s   = idx & 3;
            int u   = idx >> 2;               // 0..399
            if (u > 395) u = 395;             // tail lanes: harmless dup into pad slots
            int r   = (u * 993) >> 16;        // u / 66  (exact for u < 396)
            int px  = u - r * 66;
            int c8  = s ^ ((px ^ (px >> 2)) & 3);
            const _Float16* src = inp + ((size_t)(y0 + r) * PW + (px0 + px)) * CC
                                + c * 32 + c8 * 8;
            async_ld16(src, &lds[c * 12800 + j * 512]);   // lds base wave-uniform
        }
    }
    __syncthreads();   // drains vmcnt(0): staging + a_cur weights

    // precompute swizzled b-frag offsets (halves): [dx][half of 64px][il]
    int preoff[3][2][2];
#pragma unroll
    for (int dx = 0; dx < 3; ++dx)
#pragma unroll
        for (int h = 0; h < 2; ++h) {
            int pxv = dx + n + 32 * h;
            int sw  = (pxv ^ (pxv >> 2)) & 3;
#pragma unroll
            for (int il = 0; il < 2; ++il)
                preoff[dx][h][il] = pxv * 32 + (((il * 2 + ksub) ^ sw) * 8);
        }

#pragma unroll
    for (int c = 0; c < 2; ++c) {
#pragma unroll
        for (int tap = 0; tap < 9; ++tap) {
            int nc   = (tap == 8) ? c + 1 : c;
            int ntap = (tap == 8) ? 0 : tap + 1;
            if (nc < 2) {
#pragma unroll
                for (int o = 0; o < 2; ++o)
#pragma unroll
                    for (int il = 0; il < 2; ++il) a_nxt[o * 2 + il] = WFRAG(nc, ntap, o, il);
            }
            const int dy = tap / 3;
            const int dx = tap - dy * 3;
            const _Float16* lb = lds + c * 12800 + (w + dy) * 2112;
#pragma unroll
            for (int il = 0; il < 2; ++il) {
                half8 b0 = *(const half8*)(lb + preoff[dx][0][il]);
                half8 b1 = *(const half8*)(lb + preoff[dx][1][il]);
                acc[0][0] = __builtin_amdgcn_mfma_f32_32x32x16_f16(a_cur[il],     b0, acc[0][0], 0, 0, 0);
                acc[0][1] = __builtin_amdgcn_mfma_f32_32x32x16_f16(a_cur[il],     b1, acc[0][1], 0, 0, 0);
                acc[1][0] = __builtin_amdgcn_mfma_f32_32x32x16_f16(a_cur[2 + il], b0, acc[1][0], 0, 0, 0);
                acc[1][1] = __builtin_amdgcn_mfma_f32_32x32x16_f16(a_cur[2 + il], b1, acc[1][1], 0, 0, 0);
            }
#pragma unroll
            for (int q = 0; q < 4; ++q) a_cur[q] = a_nxt[q];
        }
    }
#undef WFRAG

    // ---- epilogue: bias + ReLU -> padded NHWC f16 interior ----
    int m = sel[t * LL + layer];
    m = __builtin_amdgcn_readfirstlane(m);
    const float* Bp = enc_b + ((size_t)layer * MM + m) * CC;
    _Float16* orow = outp + ((size_t)(y0 + w + 1) * PW + 1) * CC;
#pragma unroll
    for (int o = 0; o < 2; ++o)
#pragma unroll
        for (int j = 0; j < 2; ++j) {
            int px = px0 + j * 32 + n;
            _Float16* po = orow + (size_t)px * CC;
#pragma unroll
            for (int rg = 0; rg < 4; ++rg) {
                int oc = o * 32 + 4 * ksub + 8 * rg;
                half4 h;
#pragma unroll
                for (int k = 0; k < 4; ++k)
                    h[k] = (_Float16)fmaxf(acc[o][j][rg * 4 + k] + Bp[oc + k], 0.f);
                *(half4*)(po + oc) = h;
            }
        }
}

// ---------------------------------------------------------------------------
// Decoder: 1x1 conv 64 -> 3 (+bias), L2-normalize for task 2. Padded NHWC in.
// ---------------------------------------------------------------------------
__global__ __launch_bounds__(256) void decoder_kernel(
    const _Float16* __restrict__ in, // padded NHWC f16, per-task stride ts halves
    size_t ts,
    const float* __restrict__ dec_w, // [T][3][64]
    const float* __restrict__ dec_b, // [T][3]
    float* __restrict__ out,         // [T][B][3][H][W]
    int task0, int ntask)
{
    const int HW = HH * WW;
    int gid = blockIdx.x * 256 + threadIdx.x;
    if (gid >= ntask * BB * HW) return;
    int tz = gid / (BB * HW);
    int rem = gid - tz * (BB * HW);
    int b = rem / HW;
    int px = rem - b * HW;
    int t = task0 + tz;
    int y = px >> 7;
    int xx = px & 127;

    const _Float16* hp = in + (size_t)tz * ts + (size_t)b * IMGH
                       + ((size_t)(y + 1) * PW + xx + 1) * CC;
    const float* w = dec_w + (size_t)t * 3 * CC;

    float a0 = dec_b[t * 3 + 0];
    float a1 = dec_b[t * 3 + 1];
    float a2 = dec_b[t * 3 + 2];
#pragma unroll
    for (int cc = 0; cc < CC; cc += 8) {
        half8 h = *(const half8*)(hp + cc);
#pragma unroll
        for (int k = 0; k < 8; ++k) {
            float v = (float)h[k];
            a0 += v * w[cc + k];
            a1 += v * w[CC + cc + k];
            a2 += v * w[2 * CC + cc + k];
        }
    }
    if (t == 2) {
        float r = 1.0f / sqrtf(a0 * a0 + a1 * a1 + a2 * a2);
        a0 *= r; a1 *= r; a2 *= r;
    }
    float* ob = out + ((size_t)t * BB + b) * 3 * HW + px;
    ob[0]      = a0;
    ob[HW]     = a1;
    ob[2 * HW] = a2;
}

extern "C" void kernel_launch(void* const* d_in, const int* in_sizes, int n_in,
                              void* d_out, int out_size, void* d_ws, size_t ws_size,
                              hipStream_t stream) {
    const float* x      = (const float*)d_in[0];
    const float* alpha0 = (const float*)d_in[1];
    const float* alphas = (const float*)d_in[2];
    const float* g0     = (const float*)d_in[3];
    const float* gs     = (const float*)d_in[4];
    const float* enc_w  = (const float*)d_in[5];
    const float* enc_b  = (const float*)d_in[6];
    const float* dec_w  = (const float*)d_in[7];
    const float* dec_b  = (const float*)d_in[8];
    float* out = (float*)d_out;

    const size_t ACT = (size_t)BB * IMGH;      // halves per padded activation buffer
    char* pw = (char*)d_ws;
    int* sel = (int*)pw;                 pw += 1024;
    _Float16* W3 = (_Float16*)pw;        pw += (size_t)12 * 36864 * 2;
    _Float16* act0 = (_Float16*)pw;      pw += ACT * 2;
    _Float16* bufs = (_Float16*)pw;
    size_t base = (size_t)(pw - (char*)d_ws);
    bool fused = ws_size >= base + 6 * ACT * 2;

    routing_kernel<<<1, 64, 0, stream>>>(alpha0, alphas, g0, gs, sel);
    prep_weights<<<dim3(36, 12), 256, 0, stream>>>(enc_w, sel, W3);
    int nbuf = fused ? 7 : 3;
    zero_borders<<<dim3(nbuf * BB, 4), 256, 0, stream>>>(act0);
    to_nhwc<<<dim3(2, HH, BB), 256, 0, stream>>>(x, act0);

    if (fused) {
        _Float16* A = bufs;        // task stride 2*ACT
        _Float16* B = bufs + ACT;  // task stride 2*ACT
        size_t ts = 2 * ACT;
        conv3x3_mfma<<<dim3(64, BB, 3), 256, 0, stream>>>(act0, A, W3, enc_b, sel, 0, 0, 0,  ts);
        conv3x3_mfma<<<dim3(64, BB, 3), 256, 0, stream>>>(A,    B, W3, enc_b, sel, 1, 0, ts, ts);
        conv3x3_mfma<<<dim3(64, BB, 3), 256, 0, stream>>>(B,    A, W3, enc_b, sel, 2, 0, ts, ts);
        conv3x3_mfma<<<dim3(64, BB, 3), 256, 0, stream>>>(A,    B, W3, enc_b, sel, 3, 0, ts, ts);
        decoder_kernel<<<(3 * BB * HH * WW + 255) / 256, 256, 0, stream>>>(
            B, ts, dec_w, dec_b, out, 0, 3);
    } else {
        _Float16* A = bufs;
        _Float16* B = bufs + ACT;
        for (int t = 0; t < TT; ++t) {
            conv3x3_mfma<<<dim3(64, BB, 1), 256, 0, stream>>>(act0, A, W3, enc_b, sel, 0, t, 0, 0);
            conv3x3_mfma<<<dim3(64, BB, 1), 256, 0, stream>>>(A,    B, W3, enc_b, sel, 1, t, 0, 0);
            conv3x3_mfma<<<dim3(64, BB, 1), 256, 0, stream>>>(B,    A, W3, enc_b, sel, 2, t, 0, 0);
            conv3x3_mfma<<<dim3(64, BB, 1), 256, 0, stream>>>(A,    B, W3, enc_b, sel, 3, t, 0, 0);
            decoder_kernel<<<(BB * HH * WW + 255) / 256, 256, 0, stream>>>(
                B, 0, dec_w, dec_b, out, t, 1);
        }
    }
}

// Round 3
// 297.132 us; speedup vs baseline: 1.0765x; 1.0636x over previous
//
#include <hip/hip_runtime.h>

#define BB 8
#define CC 64
#define HH 128
#define WW 128
#define TT 3
#define LL 4
#define MM 3

#define PW 130                    // padded spatial dim
#define IMGH ((size_t)PW * PW * CC)   // halves per padded image

typedef _Float16 half8 __attribute__((ext_vector_type(8)));
typedef _Float16 half4 __attribute__((ext_vector_type(4)));
typedef float floatx16 __attribute__((ext_vector_type(16)));

__device__ __forceinline__ void async_ld16(const _Float16* g, _Float16* l) {
    __builtin_amdgcn_global_load_lds(
        (const __attribute__((address_space(1))) void*)g,
        (__attribute__((address_space(3))) void*)l, 16, 0, 0);
}

// ---------------------------------------------------------------------------
// Weight prep (+ inline routing): every block recomputes the trivial argmax
// chain for its task (60 scalar cached loads), then gathers the selected
// module, fp32 -> fp16, rearranged to A-frag order:
// W3[tl][tap][c(2)][il(2)][o(2)][lane(64)*8] -- one a-frag = contiguous 1 KB.
// Block (x=0) also publishes sel[] for the conv epilogue bias gather.
// ---------------------------------------------------------------------------
__global__ __launch_bounds__(256) void prep_weights(
    const float* __restrict__ enc_w, // [L][M][64][64][3][3]
    const float* __restrict__ alpha0,
    const float* __restrict__ alphas,
    const float* __restrict__ g0,
    const float* __restrict__ gs,
    int* __restrict__ sel,           // [T][L]
    _Float16* __restrict__ W3)       // [12][36864]
{
    int tl = blockIdx.y;
    int t = tl >> 2, layer = tl & 3;
    int idx = 0;
    for (int l = 0; l <= layer; ++l) {
        const float *a, *g;
        if (l == 0) { a = alpha0 + t * MM; g = g0 + t * MM; }
        else {
            int off = (((l - 1) * TT + t) * MM + idx) * MM;
            a = alphas + off; g = gs + off;
        }
        float best = a[0] + g[0];
        int bi = 0;
        for (int j = 1; j < MM; ++j) {
            float v = a[j] + g[j];
            if (v > best) { best = v; bi = j; }
        }
        idx = bi;
    }
    const int m = idx;
    if (blockIdx.x == 0 && threadIdx.x == 0) sel[tl] = m;

    const float* src = enc_w + ((size_t)layer * MM + m) * (CC * CC * 9);
    _Float16* dst = W3 + (size_t)tl * 36864;
    for (int i = blockIdx.x * 256 + threadIdx.x; i < 36864; i += gridDim.x * 256) {
        int j   = i & 7;
        int l   = (i >> 3) & 63;
        int o   = (i >> 9) & 1;
        int il  = (i >> 10) & 1;
        int c   = (i >> 11) & 1;
        int tap = i >> 12;                      // 0..8
        int oc  = o * 32 + (l & 31);
        int kch = c * 32 + il * 16 + (l >> 5) * 8 + j;
        dst[i] = (_Float16)src[(oc * CC + kch) * 9 + tap];
    }
}

// ---------------------------------------------------------------------------
// Zero the 1-px borders of padded NHWC images (contiguous buffers).
// ---------------------------------------------------------------------------
__global__ __launch_bounds__(256) void zero_borders(_Float16* __restrict__ base0)
{
    _Float16* base = base0 + (size_t)blockIdx.x * IMGH;
    const int i0 = blockIdx.y * 1032;
    for (int i = i0 + threadIdx.x; i < i0 + 1032; i += 256) {
        int px_idx = i >> 3, q = i & 7;   // 516 border px * 8 half8-chunks
        int row, col;
        if (px_idx < 130)      { row = 0;            col = px_idx; }
        else if (px_idx < 260) { row = 129;          col = px_idx - 130; }
        else if (px_idx < 388) { row = px_idx - 259; col = 0; }
        else                   { row = px_idx - 387; col = 129; }
        half8 z = {};
        *(half8*)(base + ((size_t)row * PW + col) * CC + q * 8) = z;
    }
}

// ---------------------------------------------------------------------------
// x: NCHW fp32 -> padded NHWC f16 (interior). Lane = px, LDS transpose.
// ---------------------------------------------------------------------------
__global__ __launch_bounds__(256) void to_nhwc(
    const float* __restrict__ x,    // [B][64][128][128]
    _Float16* __restrict__ act0)    // [B][130][130][64] padded
{
    const int xs = blockIdx.x;  // 0..1
    const int y  = blockIdx.y;  // 0..127
    const int b  = blockIdx.z;  // 0..7

    __shared__ _Float16 lds[64 * 72];  // [px][ch], pad 72

    const int wv = threadIdx.x >> 6;
    const int l  = threadIdx.x & 63;
    const float* src = x + ((size_t)b * CC * HH + y) * WW + xs * 64 + l;
#pragma unroll
    for (int k = 0; k < 16; ++k) {
        int ch = wv * 16 + k;
        lds[l * 72 + ch] = (_Float16)src[(size_t)ch * HH * WW];
    }
    __syncthreads();
    int px = threadIdx.x >> 2;
    int q  = threadIdx.x & 3;
    _Float16* dst = act0 + (size_t)b * IMGH
                  + ((size_t)(y + 1) * PW + xs * 64 + px + 1) * CC + q * 16;
    *(half8*)dst       = *(const half8*)&lds[px * 72 + q * 16];
    *(half8*)(dst + 8) = *(const half8*)&lds[px * 72 + q * 16 + 8];
}

// ---------------------------------------------------------------------------
// 3x3 SAME conv + bias + ReLU on padded NHWC f16, MFMA 32x32x16.
// Block 256 thr / 4 waves; block tile = 8 output rows x 64 px x 64 oc.
// Wave = 2 output rows.  Per 32-ch chunk: act tile (10x66, XOR-swizzled
// 16B slots) AND that chunk's weight frags (36.9KB, linear) are DMA-staged
// into LDS via global_load_lds, one barrier, then 9 fully-unrolled tap
// phases of pure {ds_read a+b -> 16 MFMA} with no global loads and no
// register-copy pipeline (compiler schedules freely across taps).
// LDS 79.9 KB -> 2 blocks/CU.  Weight global traffic: 72 KB/block (was
// 288 KB): 442 -> 55 MB/layer.
// ---------------------------------------------------------------------------
__global__ __launch_bounds__(256, 2) void conv3x3_mfma(
    const _Float16* __restrict__ in,   // padded NHWC per task (stride tsi halves)
    _Float16* __restrict__ out,        // padded NHWC per task (stride tso halves)
    const _Float16* __restrict__ W3,   // [12][36864]
    const float* __restrict__ enc_b,   // [L][M][64]
    const int* __restrict__ sel,
    int layer, int task0, size_t tsi, size_t tso)
{
    const int y0  = (blockIdx.x >> 1) * 8;   // padded row of halo top
    const int px0 = (blockIdx.x & 1) * 64;   // padded col of halo left
    const int b   = blockIdx.y;
    const int tz  = blockIdx.z;
    const int t   = task0 + tz;

    const _Float16* inp = in + (size_t)tz * tsi + (size_t)b * IMGH;
    _Float16* outp      = out + (size_t)tz * tso + (size_t)b * IMGH;
    const int tl = t * LL + layer;
    const _Float16* Wt = W3 + (size_t)tl * 36864;

    const int tid  = threadIdx.x;
    const int lane = tid & 63;
    const int w    = tid >> 6;        // wave id; rows 2w, 2w+1 of the 8
    const int n    = lane & 31;
    const int ksub = lane >> 5;

    // act: 660 px-slots (10 rows x 66 px) x 4 x 16B + 48 pad slots = 43008 B
    // wts: 9 taps x 4 frags x 1 KB = 36864 B            -> total 79872 B
    __shared__ __align__(16) _Float16 lds[21504 + 18432];
    _Float16* actl = lds;
    _Float16* wl   = lds + 21504;

    floatx16 acc[2][2][2];   // [rr][o][j]
#pragma unroll
    for (int rr = 0; rr < 2; ++rr)
#pragma unroll
        for (int o = 0; o < 2; ++o)
#pragma unroll
            for (int j = 0; j < 2; ++j)
#pragma unroll
                for (int i = 0; i < 16; ++i) acc[rr][o][j][i] = 0.f;

    // swizzled b-frag offsets (halves): [dx][half of 64px][il]
    int preoff[3][2][2];
#pragma unroll
    for (int dx = 0; dx < 3; ++dx)
#pragma unroll
        for (int h = 0; h < 2; ++h) {
            int pxv = dx + n + 32 * h;
            int sw  = (pxv ^ (pxv >> 2)) & 3;
#pragma unroll
            for (int il = 0; il < 2; ++il)
                preoff[dx][h][il] = pxv * 32 + (((il * 2 + ksub) ^ sw) * 8);
        }

    for (int c = 0; c < 2; ++c) {
        if (c) __syncthreads();   // all reads of previous chunk done
        // ---- DMA-stage act chunk: 42 x 1KB wave-ops ----
#pragma unroll
        for (int jj = 0; jj < 11; ++jj) {
            int j = w + jj * 4;
            if (j < 42) {
                int idx = j * 64 + lane;          // 16B-slot index
                int s   = idx & 3;
                int u   = idx >> 2;               // px-slot 0..671
                if (u > 659) u = 659;             // tail dups land in LDS pad
                int r   = (u * 993) >> 16;        // u / 66 (exact, u<660)
                int px  = u - r * 66;
                int c8  = s ^ ((px ^ (px >> 2)) & 3);
                const _Float16* src = inp + ((size_t)(y0 + r) * PW + (px0 + px)) * CC
                                    + c * 32 + c8 * 8;
                async_ld16(src, actl + j * 512);
            }
        }
        // ---- DMA-stage weight chunk: 36 x 1KB wave-ops (linear) ----
#pragma unroll
        for (int kk = 0; kk < 9; ++kk) {
            int k = w + kk * 4;                   // 0..35 exactly
            const _Float16* src = Wt + ((k >> 2) * 4096 + c * 2048 + (k & 3) * 512)
                                + lane * 8;
            async_ld16(src, wl + k * 512);
        }
        __syncthreads();   // drains vmcnt(0)

#pragma unroll
        for (int tap = 0; tap < 9; ++tap) {
            const int dy = tap / 3;
            const int dx = tap - dy * 3;
            half8 afr[2][2];   // [il][o]
#pragma unroll
            for (int il = 0; il < 2; ++il)
#pragma unroll
                for (int o = 0; o < 2; ++o)
                    afr[il][o] = *(const half8*)(wl + tap * 2048 + il * 1024
                                                 + o * 512 + lane * 8);
#pragma unroll
            for (int rr = 0; rr < 2; ++rr) {
                const _Float16* lb = actl + (2 * w + rr + dy) * 2112; // 66*32
#pragma unroll
                for (int il = 0; il < 2; ++il) {
                    half8 b0 = *(const half8*)(lb + preoff[dx][0][il]);
                    half8 b1 = *(const half8*)(lb + preoff[dx][1][il]);
                    acc[rr][0][0] = __builtin_amdgcn_mfma_f32_32x32x16_f16(afr[il][0], b0, acc[rr][0][0], 0, 0, 0);
                    acc[rr][0][1] = __builtin_amdgcn_mfma_f32_32x32x16_f16(afr[il][0], b1, acc[rr][0][1], 0, 0, 0);
                    acc[rr][1][0] = __builtin_amdgcn_mfma_f32_32x32x16_f16(afr[il][1], b0, acc[rr][1][0], 0, 0, 0);
                    acc[rr][1][1] = __builtin_amdgcn_mfma_f32_32x32x16_f16(afr[il][1], b1, acc[rr][1][1], 0, 0, 0);
                }
            }
        }
    }

    // ---- epilogue: bias + ReLU -> padded NHWC f16 interior ----
    int m = sel[t * LL + layer];
    m = __builtin_amdgcn_readfirstlane(m);
    const float* Bp = enc_b + ((size_t)layer * MM + m) * CC;
#pragma unroll
    for (int rr = 0; rr < 2; ++rr) {
        _Float16* orow = outp + ((size_t)(y0 + 2 * w + rr + 1) * PW + 1) * CC;
#pragma unroll
        for (int o = 0; o < 2; ++o)
#pragma unroll
            for (int j = 0; j < 2; ++j) {
                int px = px0 + j * 32 + n;
                _Float16* po = orow + (size_t)px * CC;
#pragma unroll
                for (int rg = 0; rg < 4; ++rg) {
                    int oc = o * 32 + 4 * ksub + 8 * rg;
                    half4 h;
#pragma unroll
                    for (int k = 0; k < 4; ++k)
                        h[k] = (_Float16)fmaxf(acc[rr][o][j][rg * 4 + k] + Bp[oc + k], 0.f);
                    *(half4*)(po + oc) = h;
                }
            }
    }
}

// ---------------------------------------------------------------------------
// Decoder: 1x1 conv 64 -> 3 (+bias), L2-normalize for task 2. Padded NHWC in.
// ---------------------------------------------------------------------------
__global__ __launch_bounds__(256) void decoder_kernel(
    const _Float16* __restrict__ in, // padded NHWC f16, per-task stride ts halves
    size_t ts,
    const float* __restrict__ dec_w, // [T][3][64]
    const float* __restrict__ dec_b, // [T][3]
    float* __restrict__ out,         // [T][B][3][H][W]
    int task0, int ntask)
{
    const int HW = HH * WW;
    int gid = blockIdx.x * 256 + threadIdx.x;
    if (gid >= ntask * BB * HW) return;
    int tz = gid / (BB * HW);
    int rem = gid - tz * (BB * HW);
    int b = rem / HW;
    int px = rem - b * HW;
    int t = task0 + tz;
    int y = px >> 7;
    int xx = px & 127;

    const _Float16* hp = in + (size_t)tz * ts + (size_t)b * IMGH
                       + ((size_t)(y + 1) * PW + xx + 1) * CC;
    const float* w = dec_w + (size_t)t * 3 * CC;

    float a0 = dec_b[t * 3 + 0];
    float a1 = dec_b[t * 3 + 1];
    float a2 = dec_b[t * 3 + 2];
#pragma unroll
    for (int cc = 0; cc < CC; cc += 8) {
        half8 h = *(const half8*)(hp + cc);
#pragma unroll
        for (int k = 0; k < 8; ++k) {
            float v = (float)h[k];
            a0 += v * w[cc + k];
            a1 += v * w[CC + cc + k];
            a2 += v * w[2 * CC + cc + k];
        }
    }
    if (t == 2) {
        float r = 1.0f / sqrtf(a0 * a0 + a1 * a1 + a2 * a2);
        a0 *= r; a1 *= r; a2 *= r;
    }
    float* ob = out + ((size_t)t * BB + b) * 3 * HW + px;
    ob[0]      = a0;
    ob[HW]     = a1;
    ob[2 * HW] = a2;
}

extern "C" void kernel_launch(void* const* d_in, const int* in_sizes, int n_in,
                              void* d_out, int out_size, void* d_ws, size_t ws_size,
                              hipStream_t stream) {
    const float* x      = (const float*)d_in[0];
    const float* alpha0 = (const float*)d_in[1];
    const float* alphas = (const float*)d_in[2];
    const float* g0     = (const float*)d_in[3];
    const float* gs     = (const float*)d_in[4];
    const float* enc_w  = (const float*)d_in[5];
    const float* enc_b  = (const float*)d_in[6];
    const float* dec_w  = (const float*)d_in[7];
    const float* dec_b  = (const float*)d_in[8];
    float* out = (float*)d_out;

    const size_t ACT = (size_t)BB * IMGH;      // halves per padded activation buffer
    char* pw = (char*)d_ws;
    int* sel = (int*)pw;                 pw += 1024;
    _Float16* W3 = (_Float16*)pw;        pw += (size_t)12 * 36864 * 2;
    _Float16* act0 = (_Float16*)pw;      pw += ACT * 2;
    _Float16* bufs = (_Float16*)pw;
    size_t base = (size_t)(pw - (char*)d_ws);
    bool fused = ws_size >= base + 6 * ACT * 2;

    prep_weights<<<dim3(36, 12), 256, 0, stream>>>(enc_w, alpha0, alphas, g0, gs, sel, W3);
    int nbuf = fused ? 7 : 3;
    zero_borders<<<dim3(nbuf * BB, 4), 256, 0, stream>>>(act0);
    to_nhwc<<<dim3(2, HH, BB), 256, 0, stream>>>(x, act0);

    if (fused) {
        _Float16* A = bufs;        // task stride 2*ACT
        _Float16* B = bufs + ACT;  // task stride 2*ACT
        size_t ts = 2 * ACT;
        conv3x3_mfma<<<dim3(32, BB, 3), 256, 0, stream>>>(act0, A, W3, enc_b, sel, 0, 0, 0,  ts);
        conv3x3_mfma<<<dim3(32, BB, 3), 256, 0, stream>>>(A,    B, W3, enc_b, sel, 1, 0, ts, ts);
        conv3x3_mfma<<<dim3(32, BB, 3), 256, 0, stream>>>(B,    A, W3, enc_b, sel, 2, 0, ts, ts);
        conv3x3_mfma<<<dim3(32, BB, 3), 256, 0, stream>>>(A,    B, W3, enc_b, sel, 3, 0, ts, ts);
        decoder_kernel<<<(3 * BB * HH * WW + 255) / 256, 256, 0, stream>>>(
            B, ts, dec_w, dec_b, out, 0, 3);
    } else {
        _Float16* A = bufs;
        _Float16* B = bufs + ACT;
        for (int t = 0; t < TT; ++t) {
            conv3x3_mfma<<<dim3(32, BB, 1), 256, 0, stream>>>(act0, A, W3, enc_b, sel, 0, t, 0, 0);
            conv3x3_mfma<<<dim3(32, BB, 1), 256, 0, stream>>>(A,    B, W3, enc_b, sel, 1, t, 0, 0);
            conv3x3_mfma<<<dim3(32, BB, 1), 256, 0, stream>>>(B,    A, W3, enc_b, sel, 2, t, 0, 0);
            conv3x3_mfma<<<dim3(32, BB, 1), 256, 0, stream>>>(A,    B, W3, enc_b, sel, 3, t, 0, 0);
            decoder_kernel<<<(BB * HH * WW + 255) / 256, 256, 0, stream>>>(
                B, 0, dec_w, dec_b, out, t, 1);
        }
    }
}